// Round 6
// baseline (255.513 us; speedup 1.0000x reference)
//
#include <hip/hip_runtime.h>

typedef short short8 __attribute__((ext_vector_type(8)));
typedef float f32x4 __attribute__((ext_vector_type(4)));

__device__ inline unsigned short f2bf(float f) {
    unsigned u = __builtin_bit_cast(unsigned, f);
    u += 0x7fff + ((u >> 16) & 1);   // round-to-nearest-even
    return (unsigned short)(u >> 16);
}
__device__ inline short8 as_short8(uint4 v) { return __builtin_bit_cast(short8, v); }

// ---------------- Kernel 1: repack qt+v to bf16 MFMA fragment order, and (blocks
// 2048..2055) precompute the combined low-rank weight W = ((W_A@W_B)@W_Bt)@W_At
// [64x64] f32 per head. Pure f32 re-association of the reference chain (error ~1e-7,
// far below the bf16 noise floor); lets attn phase 0 collapse from 4 chained matmuls
// (5 barriers, ~640 LDS reads/thread) to ONE 16x64x64 matmul (1 barrier, ~512 reads).
__global__ __launch_bounds__(256) void repack_kernel(const float* __restrict__ qt,
                                                     const float* __restrict__ v,
                                                     const float* __restrict__ WA,
                                                     const float* __restrict__ WB,
                                                     const float* __restrict__ WBt,
                                                     const float* __restrict__ WAt,
                                                     uint4* __restrict__ qtp,
                                                     uint4* __restrict__ vp,
                                                     float* __restrict__ Wc) {
    const int tid = threadIdx.x;
    if (blockIdx.x >= 2048) {
        // ---- combined-W block for head h
        __shared__ float WAl[64 * 32];    // 8 KB
        __shared__ float WBl[32 * 16];    // 2 KB
        __shared__ float WBtl[16 * 32];   // 2 KB
        __shared__ float WAtl[32 * 64];   // 8 KB
        __shared__ float T1[64 * 16];     // 4 KB
        __shared__ float T2[64 * 32];     // 8 KB
        int h = blockIdx.x - 2048;        // 0..7
#pragma unroll
        for (int i = 0; i < 8; ++i) WAl[i * 256 + tid] = WA[h * 2048 + i * 256 + tid];
#pragma unroll
        for (int i = 0; i < 2; ++i) WBl[i * 256 + tid] = WB[h * 512 + i * 256 + tid];
#pragma unroll
        for (int i = 0; i < 2; ++i) WBtl[i * 256 + tid] = WBt[h * 512 + i * 256 + tid];
#pragma unroll
        for (int i = 0; i < 8; ++i) WAtl[i * 256 + tid] = WAt[h * 2048 + i * 256 + tid];
        __syncthreads();
        // T1[64x16] = WA @ WB
#pragma unroll
        for (int i = 0; i < 4; ++i) {
            int e = i * 256 + tid;
            int r = e >> 4, c = e & 15;
            float s = 0.f;
#pragma unroll
            for (int j = 0; j < 32; ++j) s += WAl[r * 32 + j] * WBl[j * 16 + c];
            T1[e] = s;
        }
        __syncthreads();
        // T2[64x32] = T1 @ WBt
#pragma unroll
        for (int i = 0; i < 8; ++i) {
            int e = i * 256 + tid;
            int r = e >> 5, c = e & 31;
            float s = 0.f;
#pragma unroll
            for (int j = 0; j < 16; ++j) s += T1[r * 16 + j] * WBtl[j * 32 + c];
            T2[e] = s;
        }
        __syncthreads();
        // Wc[h][64x64] = T2 @ WAt
#pragma unroll
        for (int i = 0; i < 16; ++i) {
            int e = i * 256 + tid;
            int r = e >> 6, c = e & 63;
            float s = 0.f;
#pragma unroll
            for (int j = 0; j < 32; ++j) s += T2[r * 32 + j] * WAtl[j * 64 + c];
            Wc[h * 4096 + e] = s;
        }
        return;
    }
    // ---- repack blocks
    int g = blockIdx.x * 256 + tid;   // < 524288
    int lane = g & 63;
    const float* src;
    uint4* dst;
    size_t jstride;
    if (g < 262144) {
        int kc = (g >> 6) & 1;
        int nt = (g >> 7) & 63;
        int bh = g >> 13;
        int k = kc * 32 + (lane >> 4) * 8;
        int n = nt * 16 + (lane & 15);
        src = qt + ((size_t)bh * 64 + k) * 1024 + n;
        jstride = 1024;
        dst = qtp + g;
    } else {
        int g2 = g - 262144;
        int kc = (g2 >> 6) & 31;
        int nt = (g2 >> 11) & 3;
        int bh = g2 >> 13;
        int k = kc * 32 + (lane >> 4) * 8;
        int n = nt * 16 + (lane & 15);
        src = v + ((size_t)bh * 1024 + k) * 64 + n;
        jstride = 64;
        dst = vp + g2;
    }
    unsigned short e[8];
#pragma unroll
    for (int j = 0; j < 8; ++j) e[j] = f2bf(src[jstride * j]);
    uint4 o;
    o.x = e[0] | ((unsigned)e[1] << 16);
    o.y = e[2] | ((unsigned)e[3] << 16);
    o.z = e[4] | ((unsigned)e[5] << 16);
    o.w = e[6] | ((unsigned)e[7] << 16);
    *dst = o;
}

// ---------------- Kernel 2: phase0 Qp = q@Wc -> logits -> softmax -> P@V -> stores
// Block: 256 threads (4 waves), 16 Q-rows of one (b,h).
//
// Phase 0: Qp[16][64] = qrow @ Wc[h] * (LOG2E/8) in bf16, one matmul, one barrier.
// Staging buffers (20 KB) are dead before Pbuf is written -> union (LDS 35.6 KB,
// 4 blocks/CU).
//
// OPERAND-SWAPPED MFMAs: S^T tiles via mfma(qt_frag, Qp_frag, .). D layout:
// row=kcol(quad*4+r), col=qrow(l16): lane owns 4 consecutive attn columns of ONE row.
//
// PHASE ORDER (vmcnt-aware): exp2 -> UNNORMALIZED P to LDS (independent of the
// cross-wave sum) -> one barrier (covers P + redsum) -> PV on unnormalized P ->
// o *= inv (inv is row l16's, exactly the row this lane holds) -> out store ->
// attn nt-stores LAST. PV's vb loads no longer queue behind 64 nt-stores in the
// in-order vmcnt queue; the attn store stream drains while other resident blocks
// compute. Softmax uses a FIXED shift (logits bounded); exact after normalization.
// Grid swizzle: bh = blockIdx & 31 -> all 64 blocks of a bh land on XCD bh%8 = h,
// so each XCD reads exactly one head's Wc (16 KB, L2-local).
__global__ __launch_bounds__(256, 4) void attn_kernel(
    const float* __restrict__ q,
    const float* __restrict__ Wc,
    const uint4* __restrict__ qtp,
    const uint4* __restrict__ vp,
    float* __restrict__ outp,
    float* __restrict__ attnp) {
    constexpr int PST = 1032;  // bf16 elems per P row (1024 + 8 pad)
    __shared__ __align__(16) union {
        struct {
            float qrow[16 * 64];   // 4 KB
            float Wl[64 * 64];     // 16 KB
        } s;                                  // 20480 B
        unsigned short Pbuf[16 * PST];        // 33024 B
    } u;
    __shared__ __align__(16) unsigned short Qpl[16 * 72];  // 2304 B (72: pad vs bank conflicts)
    __shared__ float redsum[4][16];

    const int tid = threadIdx.x;
    const int w = tid >> 6, lane = tid & 63;
    const int quad = lane >> 4, l16 = lane & 15;
    const int bh = blockIdx.x & 31;
    const int mblk = blockIdx.x >> 5;
    const int b = bh >> 3, h = bh & 7;
    const int rb = mblk * 16;
    const int rowbase = bh * 1024 + rb;   // global Q-row base

    // ================= Phase 0: Qp = qrow @ Wc[h] for this block's 16 rows ========
#pragma unroll
    for (int i = 0; i < 4; ++i) {
        int e = i * 256 + tid;        // row*64 + k
        int row = e >> 6, k = e & 63;
        u.s.qrow[e] = q[((size_t)(b * 1024 + rb + row) * 8 + h) * 64 + k];
    }
#pragma unroll
    for (int i = 0; i < 16; ++i) u.s.Wl[i * 256 + tid] = Wc[h * 4096 + i * 256 + tid];
    __syncthreads();
    constexpr float QSCALE = 0.125f * 1.4426950408889634f;
#pragma unroll
    for (int i = 0; i < 4; ++i) {
        int e = i * 256 + tid;
        int row = e >> 6, k = e & 63;    // qrow broadcast across 64 lanes; Wl 2-way free
        float s = 0.f;
#pragma unroll
        for (int j = 0; j < 64; ++j) s += u.s.qrow[row * 64 + j] * u.s.Wl[j * 64 + k];
        Qpl[row * 72 + k] = f2bf(s * QSCALE);
    }
    __syncthreads();
    // NOTE: all union .s reads are complete; Pbuf may be written after this point.

    // ---- Qp fragments (row l16, pre-scaled by log2(e)/8); B operand of swapped QK^T.
    const unsigned short* qpl = &Qpl[l16 * 72 + quad * 8];
    short8 a0 = as_short8(*(const uint4*)(qpl));        // k = quad*8 .. +7
    short8 a1 = as_short8(*(const uint4*)(qpl + 32));   // k = 32 + quad*8 .. +7

    // ---- QK^T (transposed): 16 col-tiles of 16 per wave, K=64.
    // acc[t][r] = logit*log2(e) at qrow=l16, kcol = w*256 + t*16 + quad*4 + r.
    f32x4 acc[16];
    const uint4* qtb = qtp + (size_t)bh * 8192 + lane;
#pragma unroll
    for (int t = 0; t < 16; ++t) {
        int nt = w * 16 + t;
        uint4 b0 = qtb[(nt * 2 + 0) * 64];
        uint4 b1 = qtb[(nt * 2 + 1) * 64];
        f32x4 z = {0.f, 0.f, 0.f, 0.f};
        z = __builtin_amdgcn_mfma_f32_16x16x32_bf16(as_short8(b0), a0, z, 0, 0, 0);
        acc[t] = __builtin_amdgcn_mfma_f32_16x16x32_bf16(as_short8(b1), a1, z, 0, 0, 0);
    }

    // ---- exp2 with fixed shift + lane-local row sum (all 64 values belong to row l16)
    constexpr float SHIFT2 = 8.0f * 1.4426950408889634f;  // logit shift of 8 in log2 domain
    float sum = 0.f;
#pragma unroll
    for (int t = 0; t < 16; ++t) {
#pragma unroll
        for (int r = 0; r < 4; ++r) {
            float p = exp2f(acc[t][r] - SHIFT2);
            acc[t][r] = p;
            sum += p;
        }
    }

    // ---- UNNORMALIZED P (bf16) to LDS immediately — independent of the cross-wave sum
    unsigned short* pbase = &u.Pbuf[l16 * PST + w * 256 + quad * 4];
#pragma unroll
    for (int t = 0; t < 16; ++t) {
        uint2 d;
        d.x = f2bf(acc[t][0]) | ((unsigned)f2bf(acc[t][1]) << 16);
        d.y = f2bf(acc[t][2]) | ((unsigned)f2bf(acc[t][3]) << 16);
        *reinterpret_cast<uint2*>(pbase + t * 16) = d;
    }
    // cross-quad reduction (lanes sharing l16): hops 16 and 32 only
    sum += __shfl_xor(sum, 16, 64);
    sum += __shfl_xor(sum, 32, 64);
    if (lane < 16) redsum[w][l16] = sum;

    // ---- prefetch first PV B-fragments (in flight across the barrier)
    const uint4* vb = vp + (size_t)bh * 8192 + (size_t)w * 32 * 64 + lane;
    uint4 pf0 = vb[0 * 64];
    uint4 pf1 = vb[1 * 64];
    uint4 pf2 = vb[2 * 64];
    uint4 pf3 = vb[3 * 64];

    __syncthreads();   // covers Pbuf writes + redsum writes
    const float inv = 1.0f / (redsum[0][l16] + redsum[1][l16] +
                              redsum[2][l16] + redsum[3][l16]);

    // ---- P @ V on unnormalized P (swapped): lane holds out[qrow=l16][dv=w*16+quad*4+r]
    f32x4 o = {0.f, 0.f, 0.f, 0.f};
    const unsigned short* prow = &u.Pbuf[l16 * PST + quad * 8];
#pragma unroll
    for (int kc = 0; kc < 32; ++kc) {
        short8 a = as_short8(*(const uint4*)(prow + kc * 32));
        uint4 bfrag = (kc == 0) ? pf0 : (kc == 1) ? pf1 : (kc == 2) ? pf2 : (kc == 3) ? pf3
                                      : vb[kc * 64];
        o = __builtin_amdgcn_mfma_f32_16x16x32_bf16(as_short8(bfrag), a, o, 0, 0, 0);
    }
    o[0] *= inv; o[1] *= inv; o[2] *= inv; o[3] *= inv;
    __builtin_nontemporal_store(
        o, reinterpret_cast<f32x4*>(outp + ((size_t)(rowbase + l16)) * 64 + w * 16 + quad * 4));

    // ---- attn (f32, normalized) nt-store stream LAST: fire-and-forget, drains while
    // other resident blocks compute (acc still live).
    float* abase = attnp + ((size_t)(rowbase + l16)) * 1024 + w * 256 + quad * 4;
#pragma unroll
    for (int t = 0; t < 16; ++t) {
        f32x4 p;
        p[0] = acc[t][0] * inv;
        p[1] = acc[t][1] * inv;
        p[2] = acc[t][2] * inv;
        p[3] = acc[t][3] * inv;
        __builtin_nontemporal_store(p, reinterpret_cast<f32x4*>(abase + t * 16));
    }
}

extern "C" void kernel_launch(void* const* d_in, const int* in_sizes, int n_in,
                              void* d_out, int out_size, void* d_ws, size_t ws_size,
                              hipStream_t stream) {
    (void)in_sizes; (void)n_in; (void)out_size; (void)ws_size;
    const float* q   = (const float*)d_in[0];   // [4,1024,8,64]
    const float* WA  = (const float*)d_in[1];   // [8,64,32]
    const float* WB  = (const float*)d_in[2];   // [8,32,16]
    const float* WAt = (const float*)d_in[3];   // [8,32,64]
    const float* WBt = (const float*)d_in[4];   // [8,16,32]
    const float* qt  = (const float*)d_in[5];   // [4,8,64,1024]
    const float* v   = (const float*)d_in[6];   // [4,8,1024,64]

    float* outp  = (float*)d_out;                           // [4,8,1024,64]
    float* attnp = outp + (size_t)4 * 8 * 1024 * 64;        // [4,8,1024,1024]

    char* ws = (char*)d_ws;
    uint4* qtp = (uint4*)ws;                                // 4 MB
    uint4* vp  = (uint4*)(ws + 4194304);                    // 4 MB
    float* Wc  = (float*)(ws + 2 * 4194304);                // 128 KB combined weights

    hipLaunchKernelGGL(repack_kernel, dim3(2056), dim3(256), 0, stream,
                       qt, v, WA, WB, WBt, WAt, qtp, vp, Wc);
    hipLaunchKernelGGL(attn_kernel, dim3(2048), dim3(256), 0, stream,
                       q, Wc, qtp, vp, outp, attnp);
}

// Round 7
// 243.573 us; speedup vs baseline: 1.0490x; 1.0490x over previous
//
#include <hip/hip_runtime.h>

typedef short short8 __attribute__((ext_vector_type(8)));
typedef float f32x4 __attribute__((ext_vector_type(4)));

__device__ inline unsigned short f2bf(float f) {
    unsigned u = __builtin_bit_cast(unsigned, f);
    u += 0x7fff + ((u >> 16) & 1);   // round-to-nearest-even
    return (unsigned short)(u >> 16);
}
__device__ inline short8 as_short8(uint4 v) { return __builtin_bit_cast(short8, v); }

// ---------------- Kernel 1: repack qt+v to bf16 MFMA fragment order, and (blocks
// 2048..2055) precompute the combined low-rank weight W = ((W_A@W_B)@W_Bt)@W_At
// [64x64] f32 per head. Pure f32 re-association of the reference chain (error ~1e-7,
// far below the bf16 noise floor); lets attn phase 0 collapse from 4 chained matmuls
// (5 barriers, ~640 LDS reads/thread) to ONE 16x64x64 matmul (1 barrier, ~512 reads).
__global__ __launch_bounds__(256) void repack_kernel(const float* __restrict__ qt,
                                                     const float* __restrict__ v,
                                                     const float* __restrict__ WA,
                                                     const float* __restrict__ WB,
                                                     const float* __restrict__ WBt,
                                                     const float* __restrict__ WAt,
                                                     uint4* __restrict__ qtp,
                                                     uint4* __restrict__ vp,
                                                     float* __restrict__ Wc) {
    const int tid = threadIdx.x;
    if (blockIdx.x >= 2048) {
        // ---- combined-W block for head h
        __shared__ float WAl[64 * 32];    // 8 KB
        __shared__ float WBl[32 * 16];    // 2 KB
        __shared__ float WBtl[16 * 32];   // 2 KB
        __shared__ float WAtl[32 * 64];   // 8 KB
        __shared__ float T1[64 * 16];     // 4 KB
        __shared__ float T2[64 * 32];     // 8 KB
        int h = blockIdx.x - 2048;        // 0..7
#pragma unroll
        for (int i = 0; i < 8; ++i) WAl[i * 256 + tid] = WA[h * 2048 + i * 256 + tid];
#pragma unroll
        for (int i = 0; i < 2; ++i) WBl[i * 256 + tid] = WB[h * 512 + i * 256 + tid];
#pragma unroll
        for (int i = 0; i < 2; ++i) WBtl[i * 256 + tid] = WBt[h * 512 + i * 256 + tid];
#pragma unroll
        for (int i = 0; i < 8; ++i) WAtl[i * 256 + tid] = WAt[h * 2048 + i * 256 + tid];
        __syncthreads();
        // T1[64x16] = WA @ WB
#pragma unroll
        for (int i = 0; i < 4; ++i) {
            int e = i * 256 + tid;
            int r = e >> 4, c = e & 15;
            float s = 0.f;
#pragma unroll
            for (int j = 0; j < 32; ++j) s += WAl[r * 32 + j] * WBl[j * 16 + c];
            T1[e] = s;
        }
        __syncthreads();
        // T2[64x32] = T1 @ WBt
#pragma unroll
        for (int i = 0; i < 8; ++i) {
            int e = i * 256 + tid;
            int r = e >> 5, c = e & 31;
            float s = 0.f;
#pragma unroll
            for (int j = 0; j < 16; ++j) s += T1[r * 16 + j] * WBtl[j * 32 + c];
            T2[e] = s;
        }
        __syncthreads();
        // Wc[h][64x64] = T2 @ WAt
#pragma unroll
        for (int i = 0; i < 16; ++i) {
            int e = i * 256 + tid;
            int r = e >> 6, c = e & 63;
            float s = 0.f;
#pragma unroll
            for (int j = 0; j < 32; ++j) s += T2[r * 32 + j] * WAtl[j * 64 + c];
            Wc[h * 4096 + e] = s;
        }
        return;
    }
    // ---- repack blocks
    int g = blockIdx.x * 256 + tid;   // < 524288
    int lane = g & 63;
    const float* src;
    uint4* dst;
    size_t jstride;
    if (g < 262144) {
        int kc = (g >> 6) & 1;
        int nt = (g >> 7) & 63;
        int bh = g >> 13;
        int k = kc * 32 + (lane >> 4) * 8;
        int n = nt * 16 + (lane & 15);
        src = qt + ((size_t)bh * 64 + k) * 1024 + n;
        jstride = 1024;
        dst = qtp + g;
    } else {
        int g2 = g - 262144;
        int kc = (g2 >> 6) & 31;
        int nt = (g2 >> 11) & 3;
        int bh = g2 >> 13;
        int k = kc * 32 + (lane >> 4) * 8;
        int n = nt * 16 + (lane & 15);
        src = v + ((size_t)bh * 1024 + k) * 64 + n;
        jstride = 64;
        dst = vp + g2;
    }
    unsigned short e[8];
#pragma unroll
    for (int j = 0; j < 8; ++j) e[j] = f2bf(src[jstride * j]);
    uint4 o;
    o.x = e[0] | ((unsigned)e[1] << 16);
    o.y = e[2] | ((unsigned)e[3] << 16);
    o.z = e[4] | ((unsigned)e[5] << 16);
    o.w = e[6] | ((unsigned)e[7] << 16);
    *dst = o;
}

// ---------------- Kernel 2: phase0 Qp = q@Wc -> logits -> softmax -> attn write -> P@V
// Block: 256 threads (4 waves), 16 Q-rows of one (b,h).
//
// Phase 0: Qp[16][64] = qrow @ Wc[h] * (LOG2E/8) in bf16, one matmul, one barrier.
// Staging buffers (20 KB) are dead before Pbuf is written -> union (LDS 35.6 KB,
// 4 blocks/CU).
//
// OPERAND-SWAPPED MFMAs: S^T tiles via mfma(qt_frag, Qp_frag, .). D layout:
// row=kcol(quad*4+r), col=qrow(l16): lane owns 4 consecutive attn columns of ONE row.
//
// TAIL ORDER = round-5 measured structure (NOT the round-6 reorder, which regressed
// +36us -- attributed to acc[16] held live through PV exceeding the 128-VGPR cap of
// launch_bounds(256,4) -> scratch spills): reduce -> barrier -> inv -> prefetch ->
// {normalized attn nt-store + normalized P->LDS} -> barrier -> PV -> out store.
// acc dies at the end of the store loop, before PV needs its registers.
// Softmax uses a FIXED shift (logits bounded); exact after normalization.
// Grid swizzle: bh = blockIdx & 31 -> all 64 blocks of a bh land on XCD bh%8 = h,
// so each XCD reads exactly one head's Wc (16 KB, L2-local).
__global__ __launch_bounds__(256, 4) void attn_kernel(
    const float* __restrict__ q,
    const float* __restrict__ Wc,
    const uint4* __restrict__ qtp,
    const uint4* __restrict__ vp,
    float* __restrict__ outp,
    float* __restrict__ attnp) {
    constexpr int PST = 1032;  // bf16 elems per P row (1024 + 8 pad)
    __shared__ __align__(16) union {
        struct {
            float qrow[16 * 64];   // 4 KB
            float Wl[64 * 64];     // 16 KB
        } s;                                  // 20480 B
        unsigned short Pbuf[16 * PST];        // 33024 B
    } u;
    __shared__ __align__(16) unsigned short Qpl[16 * 72];  // 2304 B (72: pad vs bank conflicts)
    __shared__ float redsum[4][16];

    const int tid = threadIdx.x;
    const int w = tid >> 6, lane = tid & 63;
    const int quad = lane >> 4, l16 = lane & 15;
    const int bh = blockIdx.x & 31;
    const int mblk = blockIdx.x >> 5;
    const int b = bh >> 3, h = bh & 7;
    const int rb = mblk * 16;
    const int rowbase = bh * 1024 + rb;   // global Q-row base

    // ================= Phase 0: Qp = qrow @ Wc[h] for this block's 16 rows ========
#pragma unroll
    for (int i = 0; i < 4; ++i) {
        int e = i * 256 + tid;        // row*64 + k
        int row = e >> 6, k = e & 63;
        u.s.qrow[e] = q[((size_t)(b * 1024 + rb + row) * 8 + h) * 64 + k];
    }
#pragma unroll
    for (int i = 0; i < 16; ++i) u.s.Wl[i * 256 + tid] = Wc[h * 4096 + i * 256 + tid];
    __syncthreads();
    constexpr float QSCALE = 0.125f * 1.4426950408889634f;
#pragma unroll
    for (int i = 0; i < 4; ++i) {
        int e = i * 256 + tid;
        int row = e >> 6, k = e & 63;    // qrow broadcast across 64 lanes; Wl stride-1
        float s = 0.f;
#pragma unroll
        for (int j = 0; j < 64; ++j) s += u.s.qrow[row * 64 + j] * u.s.Wl[j * 64 + k];
        Qpl[row * 72 + k] = f2bf(s * QSCALE);
    }
    __syncthreads();
    // NOTE: all union .s reads are complete; Pbuf may be written after this point.

    // ---- Qp fragments (row l16, pre-scaled by log2(e)/8); B operand of swapped QK^T.
    const unsigned short* qpl = &Qpl[l16 * 72 + quad * 8];
    short8 a0 = as_short8(*(const uint4*)(qpl));        // k = quad*8 .. +7
    short8 a1 = as_short8(*(const uint4*)(qpl + 32));   // k = 32 + quad*8 .. +7

    // ---- QK^T (transposed): 16 col-tiles of 16 per wave, K=64.
    // acc[t][r] = logit*log2(e) at qrow=l16, kcol = w*256 + t*16 + quad*4 + r.
    f32x4 acc[16];
    const uint4* qtb = qtp + (size_t)bh * 8192 + lane;
#pragma unroll
    for (int t = 0; t < 16; ++t) {
        int nt = w * 16 + t;
        uint4 b0 = qtb[(nt * 2 + 0) * 64];
        uint4 b1 = qtb[(nt * 2 + 1) * 64];
        f32x4 z = {0.f, 0.f, 0.f, 0.f};
        z = __builtin_amdgcn_mfma_f32_16x16x32_bf16(as_short8(b0), a0, z, 0, 0, 0);
        acc[t] = __builtin_amdgcn_mfma_f32_16x16x32_bf16(as_short8(b1), a1, z, 0, 0, 0);
    }

    // ---- exp2 with fixed shift + lane-local row sum (all 64 values belong to row l16)
    constexpr float SHIFT2 = 8.0f * 1.4426950408889634f;  // logit shift of 8 in log2 domain
    float sum = 0.f;
#pragma unroll
    for (int t = 0; t < 16; ++t) {
#pragma unroll
        for (int r = 0; r < 4; ++r) {
            float p = exp2f(acc[t][r] - SHIFT2);
            acc[t][r] = p;
            sum += p;
        }
    }
    // cross-quad reduction (lanes sharing l16): hops 16 and 32 only
    sum += __shfl_xor(sum, 16, 64);
    sum += __shfl_xor(sum, 32, 64);
    if (lane < 16) redsum[w][l16] = sum;
    __syncthreads();
    const float inv = 1.0f / (redsum[0][l16] + redsum[1][l16] +
                              redsum[2][l16] + redsum[3][l16]);

    // ---- prefetch first PV B-fragments so they're in flight during the store stream
    const uint4* vb = vp + (size_t)bh * 8192 + (size_t)w * 32 * 64 + lane;
    uint4 pf0 = vb[0 * 64];
    uint4 pf1 = vb[1 * 64];
    uint4 pf2 = vb[2 * 64];
    uint4 pf3 = vb[3 * 64];

    // ---- write attn (f32x4, global, non-temporal) + P (4x bf16 = b64, LDS)
    float* abase = attnp + ((size_t)(rowbase + l16)) * 1024 + w * 256 + quad * 4;
    unsigned short* pbase = &u.Pbuf[l16 * PST + w * 256 + quad * 4];
#pragma unroll
    for (int t = 0; t < 16; ++t) {
        f32x4 p;
        p[0] = acc[t][0] * inv;
        p[1] = acc[t][1] * inv;
        p[2] = acc[t][2] * inv;
        p[3] = acc[t][3] * inv;
        __builtin_nontemporal_store(p, reinterpret_cast<f32x4*>(abase + t * 16));
        uint2 d;
        d.x = f2bf(p[0]) | ((unsigned)f2bf(p[1]) << 16);
        d.y = f2bf(p[2]) | ((unsigned)f2bf(p[3]) << 16);
        *reinterpret_cast<uint2*>(pbase + t * 16) = d;
    }
    __syncthreads();

    // ---- P @ V (swapped): out^T tile = mfma(v_frag, P_frag). Lane holds
    // out[qrow=l16][dv = w*16 + quad*4 + r] -> one dwordx4 store.
    f32x4 o = {0.f, 0.f, 0.f, 0.f};
    const unsigned short* prow = &u.Pbuf[l16 * PST + quad * 8];
#pragma unroll
    for (int kc = 0; kc < 32; ++kc) {
        short8 a = as_short8(*(const uint4*)(prow + kc * 32));
        uint4 bfrag = (kc == 0) ? pf0 : (kc == 1) ? pf1 : (kc == 2) ? pf2 : (kc == 3) ? pf3
                                      : vb[kc * 64];
        o = __builtin_amdgcn_mfma_f32_16x16x32_bf16(as_short8(bfrag), a, o, 0, 0, 0);
    }
    __builtin_nontemporal_store(
        o, reinterpret_cast<f32x4*>(outp + ((size_t)(rowbase + l16)) * 64 + w * 16 + quad * 4));
}

extern "C" void kernel_launch(void* const* d_in, const int* in_sizes, int n_in,
                              void* d_out, int out_size, void* d_ws, size_t ws_size,
                              hipStream_t stream) {
    (void)in_sizes; (void)n_in; (void)out_size; (void)ws_size;
    const float* q   = (const float*)d_in[0];   // [4,1024,8,64]
    const float* WA  = (const float*)d_in[1];   // [8,64,32]
    const float* WB  = (const float*)d_in[2];   // [8,32,16]
    const float* WAt = (const float*)d_in[3];   // [8,32,64]
    const float* WBt = (const float*)d_in[4];   // [8,16,32]
    const float* qt  = (const float*)d_in[5];   // [4,8,64,1024]
    const float* v   = (const float*)d_in[6];   // [4,8,1024,64]

    float* outp  = (float*)d_out;                           // [4,8,1024,64]
    float* attnp = outp + (size_t)4 * 8 * 1024 * 64;        // [4,8,1024,1024]

    char* ws = (char*)d_ws;
    uint4* qtp = (uint4*)ws;                                // 4 MB
    uint4* vp  = (uint4*)(ws + 4194304);                    // 4 MB
    float* Wc  = (float*)(ws + 2 * 4194304);                // 128 KB combined weights

    hipLaunchKernelGGL(repack_kernel, dim3(2056), dim3(256), 0, stream,
                       qt, v, WA, WB, WBt, WAt, qtp, vp, Wc);
    hipLaunchKernelGGL(attn_kernel, dim3(2048), dim3(256), 0, stream,
                       q, Wc, qtp, vp, outp, attnp);
}

// Round 8
// 222.368 us; speedup vs baseline: 1.1491x; 1.0954x over previous
//
#include <hip/hip_runtime.h>

typedef short short8 __attribute__((ext_vector_type(8)));
typedef float f32x4 __attribute__((ext_vector_type(4)));

__device__ inline unsigned short f2bf(float f) {
    unsigned u = __builtin_bit_cast(unsigned, f);
    u += 0x7fff + ((u >> 16) & 1);   // round-to-nearest-even
    return (unsigned short)(u >> 16);
}
__device__ inline short8 as_short8(uint4 v) { return __builtin_bit_cast(short8, v); }

// ---------------- Kernel 1: repack qt+v to bf16 MFMA fragment order (pure copy kernel).
// The Qp low-rank chain lives in attn_kernel phase 0 (it is per-16-row-block local,
// so a separate launch + 4MB workspace round-trip was pure overhead).
// NOTE: this is the exact round-5 source (measured 219.8us). Round 6/7 added a
// combined-W precompute (Wc) that coincided with +24..36us; resubmitting the round-5
// baseline verbatim disambiguates {Wc regression real} vs {cross-run noise}.
__global__ __launch_bounds__(256) void repack_kernel(const float* __restrict__ qt,
                                                     const float* __restrict__ v,
                                                     uint4* __restrict__ qtp,
                                                     uint4* __restrict__ vp) {
    const int tid = threadIdx.x;
    int g = blockIdx.x * 256 + tid;   // < 524288
    int lane = g & 63;
    const float* src;
    uint4* dst;
    size_t jstride;
    if (g < 262144) {
        int kc = (g >> 6) & 1;
        int nt = (g >> 7) & 63;
        int bh = g >> 13;
        int k = kc * 32 + (lane >> 4) * 8;
        int n = nt * 16 + (lane & 15);
        src = qt + ((size_t)bh * 64 + k) * 1024 + n;
        jstride = 1024;
        dst = qtp + g;
    } else {
        int g2 = g - 262144;
        int kc = (g2 >> 6) & 31;
        int nt = (g2 >> 11) & 3;
        int bh = g2 >> 13;
        int k = kc * 32 + (lane >> 4) * 8;
        int n = nt * 16 + (lane & 15);
        src = v + ((size_t)bh * 1024 + k) * 64 + n;
        jstride = 64;
        dst = vp + g2;
    }
    unsigned short e[8];
#pragma unroll
    for (int j = 0; j < 8; ++j) e[j] = f2bf(src[jstride * j]);
    uint4 o;
    o.x = e[0] | ((unsigned)e[1] << 16);
    o.y = e[2] | ((unsigned)e[3] << 16);
    o.z = e[4] | ((unsigned)e[5] << 16);
    o.w = e[6] | ((unsigned)e[7] << 16);
    *dst = o;
}

// ---------------- Kernel 2: phase0 Qp chain -> logits -> softmax -> attn write -> P@V
// Block: 256 threads (4 waves), 16 Q-rows of one (b,h).
//
// Phase 0: compute Qp[16][64] = (((q@W_A)@W_B)@W_Bt)@W_At * (LOG2E/8) in bf16
// for THIS block's 16 rows, entirely in LDS. Staging/intermediate buffers are dead
// before Pbuf is first written -> union (LDS 35.6 KB, 4 blocks/CU).
//
// OPERAND-SWAPPED MFMAs: S^T tiles via mfma(qt_frag, Qp_frag, .). D layout:
// row=kcol(quad*4+r), col=qrow(l16): lane owns 4 consecutive attn columns of ONE row ->
// dwordx4 attn stores, b64 P-writes, lane-local row sum (2 shfl hops, 1 divide).
// Same swap on P@V gives a single dwordx4 out store.
//
// Softmax uses a FIXED shift (logits bounded by the 0.1-scaled low-rank chain), so
// exp2(x - SHIFT)/sum is exact after normalization -- no row-max pass.
// Grid swizzle: bh = blockIdx & 31 -> all 64 blocks of a bh land on XCD bh%8.
// attn/out stores are non-temporal (never re-read).
__global__ __launch_bounds__(256, 4) void attn_kernel(
    const float* __restrict__ q,
    const float* __restrict__ WA,
    const float* __restrict__ WB,
    const float* __restrict__ WBt,
    const float* __restrict__ WAt,
    const uint4* __restrict__ qtp,
    const uint4* __restrict__ vp,
    float* __restrict__ outp,
    float* __restrict__ attnp) {
    constexpr int PST = 1032;  // bf16 elems per P row (1024 + 8 pad)
    __shared__ __align__(16) union {
        struct {
            float qrow[16 * 64];   // 4 KB
            float WAl[64 * 32];    // 8 KB
            float WBl[32 * 16];    // 2 KB
            float WBtl[16 * 32];   // 2 KB
            float WAtl[32 * 64];   // 8 KB
            float IA[16 * 32];     // 2 KB
            float IAB[16 * 16];    // 1 KB
            float IBT[16 * 32];    // 2 KB
        } s;                                  // 29696 B
        unsigned short Pbuf[16 * PST];        // 33024 B
    } u;
    __shared__ __align__(16) unsigned short Qpl[16 * 72];  // 2304 B (72: pad vs bank conflicts)
    __shared__ float redsum[4][16];

    const int tid = threadIdx.x;
    const int w = tid >> 6, lane = tid & 63;
    const int quad = lane >> 4, l16 = lane & 15;
    const int bh = blockIdx.x & 31;
    const int mblk = blockIdx.x >> 5;
    const int b = bh >> 3, h = bh & 7;
    const int rb = mblk * 16;
    const int rowbase = bh * 1024 + rb;   // global Q-row base

    // ================= Phase 0: Qp chain for this block's 16 rows =================
#pragma unroll
    for (int i = 0; i < 4; ++i) {
        int e = i * 256 + tid;        // row*64 + k
        int row = e >> 6, k = e & 63;
        u.s.qrow[e] = q[((size_t)(b * 1024 + rb + row) * 8 + h) * 64 + k];
    }
#pragma unroll
    for (int i = 0; i < 8; ++i) u.s.WAl[i * 256 + tid] = WA[h * 2048 + i * 256 + tid];
#pragma unroll
    for (int i = 0; i < 2; ++i) u.s.WBl[i * 256 + tid] = WB[h * 512 + i * 256 + tid];
#pragma unroll
    for (int i = 0; i < 2; ++i) u.s.WBtl[i * 256 + tid] = WBt[h * 512 + i * 256 + tid];
#pragma unroll
    for (int i = 0; i < 8; ++i) u.s.WAtl[i * 256 + tid] = WAt[h * 2048 + i * 256 + tid];
    __syncthreads();
    // IA[16x32] = qrow @ WA
#pragma unroll
    for (int i = 0; i < 2; ++i) {
        int e = i * 256 + tid;
        int row = e >> 5, c = e & 31;
        float s = 0.f;
#pragma unroll
        for (int j = 0; j < 64; ++j) s += u.s.qrow[row * 64 + j] * u.s.WAl[j * 32 + c];
        u.s.IA[e] = s;
    }
    __syncthreads();
    // IAB[16x16] = IA @ WB
    {
        int row = tid >> 4, c = tid & 15;
        float s = 0.f;
#pragma unroll
        for (int j = 0; j < 32; ++j) s += u.s.IA[row * 32 + j] * u.s.WBl[j * 16 + c];
        u.s.IAB[tid] = s;
    }
    __syncthreads();
    // IBT[16x32] = IAB @ WBt
#pragma unroll
    for (int i = 0; i < 2; ++i) {
        int e = i * 256 + tid;
        int row = e >> 5, c = e & 31;
        float s = 0.f;
#pragma unroll
        for (int j = 0; j < 16; ++j) s += u.s.IAB[row * 16 + j] * u.s.WBtl[j * 32 + c];
        u.s.IBT[e] = s;
    }
    __syncthreads();
    // Qpl[16x64 (stride 72)] = IBT @ WAt * (log2(e)/8), bf16
    constexpr float QSCALE = 0.125f * 1.4426950408889634f;
#pragma unroll
    for (int i = 0; i < 4; ++i) {
        int e = i * 256 + tid;
        int row = e >> 6, k = e & 63;
        float s = 0.f;
#pragma unroll
        for (int j = 0; j < 32; ++j) s += u.s.IBT[row * 32 + j] * u.s.WAtl[j * 64 + k];
        Qpl[row * 72 + k] = f2bf(s * QSCALE);
    }
    __syncthreads();
    // NOTE: all union .s reads are complete; Pbuf may be written after this point.

    // ---- Qp fragments (row l16, pre-scaled by log2(e)/8); B operand of swapped QK^T.
    const unsigned short* qpl = &Qpl[l16 * 72 + quad * 8];
    short8 a0 = as_short8(*(const uint4*)(qpl));        // k = quad*8 .. +7
    short8 a1 = as_short8(*(const uint4*)(qpl + 32));   // k = 32 + quad*8 .. +7

    // ---- QK^T (transposed): 16 col-tiles of 16 per wave, K=64.
    // acc[t][r] = logit*log2(e) at qrow=l16, kcol = w*256 + t*16 + quad*4 + r.
    f32x4 acc[16];
    const uint4* qtb = qtp + (size_t)bh * 8192 + lane;
#pragma unroll
    for (int t = 0; t < 16; ++t) {
        int nt = w * 16 + t;
        uint4 b0 = qtb[(nt * 2 + 0) * 64];
        uint4 b1 = qtb[(nt * 2 + 1) * 64];
        f32x4 z = {0.f, 0.f, 0.f, 0.f};
        z = __builtin_amdgcn_mfma_f32_16x16x32_bf16(as_short8(b0), a0, z, 0, 0, 0);
        acc[t] = __builtin_amdgcn_mfma_f32_16x16x32_bf16(as_short8(b1), a1, z, 0, 0, 0);
    }

    // ---- exp2 with fixed shift + lane-local row sum (all 64 values belong to row l16)
    constexpr float SHIFT2 = 8.0f * 1.4426950408889634f;  // logit shift of 8 in log2 domain
    float sum = 0.f;
#pragma unroll
    for (int t = 0; t < 16; ++t) {
#pragma unroll
        for (int r = 0; r < 4; ++r) {
            float p = exp2f(acc[t][r] - SHIFT2);
            acc[t][r] = p;
            sum += p;
        }
    }
    // cross-quad reduction (lanes sharing l16): hops 16 and 32 only
    sum += __shfl_xor(sum, 16, 64);
    sum += __shfl_xor(sum, 32, 64);
    if (lane < 16) redsum[w][l16] = sum;
    __syncthreads();
    const float inv = 1.0f / (redsum[0][l16] + redsum[1][l16] +
                              redsum[2][l16] + redsum[3][l16]);

    // ---- prefetch first PV B-fragments so they're in flight during the store stream
    const uint4* vb = vp + (size_t)bh * 8192 + (size_t)w * 32 * 64 + lane;
    uint4 pf0 = vb[0 * 64];
    uint4 pf1 = vb[1 * 64];
    uint4 pf2 = vb[2 * 64];
    uint4 pf3 = vb[3 * 64];

    // ---- write attn (f32x4, global, non-temporal) + P (4x bf16 = b64, LDS)
    float* abase = attnp + ((size_t)(rowbase + l16)) * 1024 + w * 256 + quad * 4;
    unsigned short* pbase = &u.Pbuf[l16 * PST + w * 256 + quad * 4];
#pragma unroll
    for (int t = 0; t < 16; ++t) {
        f32x4 p;
        p[0] = acc[t][0] * inv;
        p[1] = acc[t][1] * inv;
        p[2] = acc[t][2] * inv;
        p[3] = acc[t][3] * inv;
        __builtin_nontemporal_store(p, reinterpret_cast<f32x4*>(abase + t * 16));
        uint2 d;
        d.x = f2bf(p[0]) | ((unsigned)f2bf(p[1]) << 16);
        d.y = f2bf(p[2]) | ((unsigned)f2bf(p[3]) << 16);
        *reinterpret_cast<uint2*>(pbase + t * 16) = d;
    }
    __syncthreads();

    // ---- P @ V (swapped): out^T tile = mfma(v_frag, P_frag). Lane holds
    // out[qrow=l16][dv = w*16 + quad*4 + r] -> one dwordx4 store.
    f32x4 o = {0.f, 0.f, 0.f, 0.f};
    const unsigned short* prow = &u.Pbuf[l16 * PST + quad * 8];
#pragma unroll
    for (int kc = 0; kc < 32; ++kc) {
        short8 a = as_short8(*(const uint4*)(prow + kc * 32));
        uint4 bfrag = (kc == 0) ? pf0 : (kc == 1) ? pf1 : (kc == 2) ? pf2 : (kc == 3) ? pf3
                                      : vb[kc * 64];
        o = __builtin_amdgcn_mfma_f32_16x16x32_bf16(as_short8(bfrag), a, o, 0, 0, 0);
    }
    __builtin_nontemporal_store(
        o, reinterpret_cast<f32x4*>(outp + ((size_t)(rowbase + l16)) * 64 + w * 16 + quad * 4));
}

extern "C" void kernel_launch(void* const* d_in, const int* in_sizes, int n_in,
                              void* d_out, int out_size, void* d_ws, size_t ws_size,
                              hipStream_t stream) {
    (void)in_sizes; (void)n_in; (void)out_size; (void)ws_size;
    const float* q   = (const float*)d_in[0];   // [4,1024,8,64]
    const float* WA  = (const float*)d_in[1];   // [8,64,32]
    const float* WB  = (const float*)d_in[2];   // [8,32,16]
    const float* WAt = (const float*)d_in[3];   // [8,32,64]
    const float* WBt = (const float*)d_in[4];   // [8,16,32]
    const float* qt  = (const float*)d_in[5];   // [4,8,64,1024]
    const float* v   = (const float*)d_in[6];   // [4,8,1024,64]

    float* outp  = (float*)d_out;                           // [4,8,1024,64]
    float* attnp = outp + (size_t)4 * 8 * 1024 * 64;        // [4,8,1024,1024]

    char* ws = (char*)d_ws;
    uint4* qtp = (uint4*)ws;                                // 4 MB
    uint4* vp  = (uint4*)(ws + 4194304);                    // 4 MB

    hipLaunchKernelGGL(repack_kernel, dim3(2048), dim3(256), 0, stream, qt, v, qtp, vp);
    hipLaunchKernelGGL(attn_kernel, dim3(2048), dim3(256), 0, stream,
                       q, WA, WB, WBt, WAt, qtp, vp, outp, attnp);
}

// Round 9
// 222.308 us; speedup vs baseline: 1.1494x; 1.0003x over previous
//
#include <hip/hip_runtime.h>

typedef short short8 __attribute__((ext_vector_type(8)));
typedef float f32x4 __attribute__((ext_vector_type(4)));
typedef float f32x2 __attribute__((ext_vector_type(2)));

__device__ inline unsigned short f2bf(float f) {
    unsigned u = __builtin_bit_cast(unsigned, f);
    u += 0x7fff + ((u >> 16) & 1);   // round-to-nearest-even
    return (unsigned short)(u >> 16);
}
__device__ inline short8 as_short8(uint4 v) { return __builtin_bit_cast(short8, v); }

// ---------------- Kernel 1: repack qt+v to bf16 MFMA fragment order (pure copy kernel).
__global__ __launch_bounds__(256) void repack_kernel(const float* __restrict__ qt,
                                                     const float* __restrict__ v,
                                                     uint4* __restrict__ qtp,
                                                     uint4* __restrict__ vp) {
    const int tid = threadIdx.x;
    int g = blockIdx.x * 256 + tid;   // < 524288
    int lane = g & 63;
    const float* src;
    uint4* dst;
    size_t jstride;
    if (g < 262144) {
        int kc = (g >> 6) & 1;
        int nt = (g >> 7) & 63;
        int bh = g >> 13;
        int k = kc * 32 + (lane >> 4) * 8;
        int n = nt * 16 + (lane & 15);
        src = qt + ((size_t)bh * 64 + k) * 1024 + n;
        jstride = 1024;
        dst = qtp + g;
    } else {
        int g2 = g - 262144;
        int kc = (g2 >> 6) & 31;
        int nt = (g2 >> 11) & 3;
        int bh = g2 >> 13;
        int k = kc * 32 + (lane >> 4) * 8;
        int n = nt * 16 + (lane & 15);
        src = v + ((size_t)bh * 1024 + k) * 64 + n;
        jstride = 64;
        dst = vp + g2;
    }
    unsigned short e[8];
#pragma unroll
    for (int j = 0; j < 8; ++j) e[j] = f2bf(src[jstride * j]);
    uint4 o;
    o.x = e[0] | ((unsigned)e[1] << 16);
    o.y = e[2] | ((unsigned)e[3] << 16);
    o.z = e[4] | ((unsigned)e[5] << 16);
    o.w = e[6] | ((unsigned)e[7] << 16);
    *dst = o;
}

// ---------------- Kernel 2: phase0 Qp chain -> logits -> softmax -> attn write -> P@V
// Identical to the measured 219.8/222.4us champion EXCEPT phase 0 is vectorized:
// each thread produces 2-4 ADJACENT outputs (f32x2/f32x4 accumulators), so the
// B-matrix LDS read is contiguous along the output dim (b64/b128, row-major, NO
// transposes) and the A-operand is a broadcast b32/b128. Pads (qrow stride 68,
// IA/IBT stride 36) make all accesses conflict-free or 2-way (free). LDS instrs
// per thread: ~640 -> ~180. Per-output FMA order over j is PRESERVED -> output
// bit-identical to the champion. Everything after phase 0 is unchanged.
__global__ __launch_bounds__(256, 4) void attn_kernel(
    const float* __restrict__ q,
    const float* __restrict__ WA,
    const float* __restrict__ WB,
    const float* __restrict__ WBt,
    const float* __restrict__ WAt,
    const uint4* __restrict__ qtp,
    const uint4* __restrict__ vp,
    float* __restrict__ outp,
    float* __restrict__ attnp) {
    constexpr int PST = 1032;  // bf16 elems per P row (1024 + 8 pad)
    __shared__ __align__(16) union {
        struct {
            float qrow[16 * 68];   // 4.25 KB (pad 68: broadcast rows hit distinct banks)
            float WAl[64 * 32];    // 8 KB
            float WBl[32 * 16];    // 2 KB
            float WBtl[16 * 32];   // 2 KB
            float WAtl[32 * 64];   // 8 KB
            float IA[16 * 36];     // 2.25 KB (pad 36)
            float IAB[16 * 16];    // 1 KB
            float IBT[16 * 36];    // 2.25 KB (pad 36)
        } s;                                  // 30464 B
        unsigned short Pbuf[16 * PST];        // 33024 B
    } u;
    __shared__ __align__(16) unsigned short Qpl[16 * 72];  // 2304 B
    __shared__ float redsum[4][16];

    const int tid = threadIdx.x;
    const int w = tid >> 6, lane = tid & 63;
    const int quad = lane >> 4, l16 = lane & 15;
    const int bh = blockIdx.x & 31;
    const int mblk = blockIdx.x >> 5;
    const int b = bh >> 3, h = bh & 7;
    const int rb = mblk * 16;
    const int rowbase = bh * 1024 + rb;   // global Q-row base

    // ================= Phase 0: Qp chain (vectorized) =================
#pragma unroll
    for (int i = 0; i < 4; ++i) {
        int e = i * 256 + tid;        // row*64 + k
        int row = e >> 6, k = e & 63;
        u.s.qrow[row * 68 + k] = q[((size_t)(b * 1024 + rb + row) * 8 + h) * 64 + k];
    }
#pragma unroll
    for (int i = 0; i < 8; ++i) u.s.WAl[i * 256 + tid] = WA[h * 2048 + i * 256 + tid];
#pragma unroll
    for (int i = 0; i < 2; ++i) u.s.WBl[i * 256 + tid] = WB[h * 512 + i * 256 + tid];
#pragma unroll
    for (int i = 0; i < 2; ++i) u.s.WBtl[i * 256 + tid] = WBt[h * 512 + i * 256 + tid];
#pragma unroll
    for (int i = 0; i < 8; ++i) u.s.WAtl[i * 256 + tid] = WAt[h * 2048 + i * 256 + tid];
    __syncthreads();
    // IA[16x32] = qrow @ WA : thread -> (row, c2..c2+1), f32x2 accum
    {
        int row = tid >> 4, c2 = (tid & 15) * 2;
        float s0 = 0.f, s1 = 0.f;
#pragma unroll
        for (int j4 = 0; j4 < 16; ++j4) {
            f32x4 q4 = *(const f32x4*)&u.s.qrow[row * 68 + j4 * 4];
#pragma unroll
            for (int jj = 0; jj < 4; ++jj) {
                f32x2 w2 = *(const f32x2*)&u.s.WAl[(j4 * 4 + jj) * 32 + c2];
                s0 += q4[jj] * w2.x;
                s1 += q4[jj] * w2.y;
            }
        }
        f32x2 r; r.x = s0; r.y = s1;
        *(f32x2*)&u.s.IA[row * 36 + c2] = r;
    }
    __syncthreads();
    // IAB[16x16] = IA @ WB : thread -> (row, c), scalar accum, vectorized A reads
    {
        int row = tid >> 4, c = tid & 15;
        float s = 0.f;
#pragma unroll
        for (int j4 = 0; j4 < 8; ++j4) {
            f32x4 a4 = *(const f32x4*)&u.s.IA[row * 36 + j4 * 4];
#pragma unroll
            for (int jj = 0; jj < 4; ++jj) s += a4[jj] * u.s.WBl[(j4 * 4 + jj) * 16 + c];
        }
        u.s.IAB[tid] = s;
    }
    __syncthreads();
    // IBT[16x32] = IAB @ WBt : thread -> (row, c2..c2+1), f32x2 accum
    {
        int row = tid >> 4, c2 = (tid & 15) * 2;
        float s0 = 0.f, s1 = 0.f;
#pragma unroll
        for (int j4 = 0; j4 < 4; ++j4) {
            f32x4 a4 = *(const f32x4*)&u.s.IAB[row * 16 + j4 * 4];
#pragma unroll
            for (int jj = 0; jj < 4; ++jj) {
                f32x2 w2 = *(const f32x2*)&u.s.WBtl[(j4 * 4 + jj) * 32 + c2];
                s0 += a4[jj] * w2.x;
                s1 += a4[jj] * w2.y;
            }
        }
        f32x2 r; r.x = s0; r.y = s1;
        *(f32x2*)&u.s.IBT[row * 36 + c2] = r;
    }
    __syncthreads();
    // Qpl[16x64 (stride 72)] = IBT @ WAt * (log2(e)/8), bf16 : thread -> (row, k4..k4+3)
    constexpr float QSCALE = 0.125f * 1.4426950408889634f;
    {
        int row = tid >> 4, k4 = (tid & 15) * 4;
        f32x4 s = {0.f, 0.f, 0.f, 0.f};
#pragma unroll
        for (int j4 = 0; j4 < 8; ++j4) {
            f32x4 a4 = *(const f32x4*)&u.s.IBT[row * 36 + j4 * 4];
#pragma unroll
            for (int jj = 0; jj < 4; ++jj) {
                f32x4 w4 = *(const f32x4*)&u.s.WAtl[(j4 * 4 + jj) * 64 + k4];
                s += a4[jj] * w4;
            }
        }
        uint2 d;
        d.x = f2bf(s[0] * QSCALE) | ((unsigned)f2bf(s[1] * QSCALE) << 16);
        d.y = f2bf(s[2] * QSCALE) | ((unsigned)f2bf(s[3] * QSCALE) << 16);
        *(uint2*)&Qpl[row * 72 + k4] = d;
    }
    __syncthreads();
    // NOTE: all union .s reads are complete; Pbuf may be written after this point.

    // ---- Qp fragments (row l16, pre-scaled by log2(e)/8); B operand of swapped QK^T.
    const unsigned short* qpl = &Qpl[l16 * 72 + quad * 8];
    short8 a0 = as_short8(*(const uint4*)(qpl));        // k = quad*8 .. +7
    short8 a1 = as_short8(*(const uint4*)(qpl + 32));   // k = 32 + quad*8 .. +7

    // ---- QK^T (transposed): 16 col-tiles of 16 per wave, K=64.
    // acc[t][r] = logit*log2(e) at qrow=l16, kcol = w*256 + t*16 + quad*4 + r.
    f32x4 acc[16];
    const uint4* qtb = qtp + (size_t)bh * 8192 + lane;
#pragma unroll
    for (int t = 0; t < 16; ++t) {
        int nt = w * 16 + t;
        uint4 b0 = qtb[(nt * 2 + 0) * 64];
        uint4 b1 = qtb[(nt * 2 + 1) * 64];
        f32x4 z = {0.f, 0.f, 0.f, 0.f};
        z = __builtin_amdgcn_mfma_f32_16x16x32_bf16(as_short8(b0), a0, z, 0, 0, 0);
        acc[t] = __builtin_amdgcn_mfma_f32_16x16x32_bf16(as_short8(b1), a1, z, 0, 0, 0);
    }

    // ---- exp2 with fixed shift + lane-local row sum (all 64 values belong to row l16)
    constexpr float SHIFT2 = 8.0f * 1.4426950408889634f;  // logit shift of 8 in log2 domain
    float sum = 0.f;
#pragma unroll
    for (int t = 0; t < 16; ++t) {
#pragma unroll
        for (int r = 0; r < 4; ++r) {
            float p = exp2f(acc[t][r] - SHIFT2);
            acc[t][r] = p;
            sum += p;
        }
    }
    // cross-quad reduction (lanes sharing l16): hops 16 and 32 only
    sum += __shfl_xor(sum, 16, 64);
    sum += __shfl_xor(sum, 32, 64);
    if (lane < 16) redsum[w][l16] = sum;
    __syncthreads();
    const float inv = 1.0f / (redsum[0][l16] + redsum[1][l16] +
                              redsum[2][l16] + redsum[3][l16]);

    // ---- prefetch first PV B-fragments so they're in flight during the store stream
    const uint4* vb = vp + (size_t)bh * 8192 + (size_t)w * 32 * 64 + lane;
    uint4 pf0 = vb[0 * 64];
    uint4 pf1 = vb[1 * 64];
    uint4 pf2 = vb[2 * 64];
    uint4 pf3 = vb[3 * 64];

    // ---- write attn (f32x4, global, non-temporal) + P (4x bf16 = b64, LDS)
    float* abase = attnp + ((size_t)(rowbase + l16)) * 1024 + w * 256 + quad * 4;
    unsigned short* pbase = &u.Pbuf[l16 * PST + w * 256 + quad * 4];
#pragma unroll
    for (int t = 0; t < 16; ++t) {
        f32x4 p;
        p[0] = acc[t][0] * inv;
        p[1] = acc[t][1] * inv;
        p[2] = acc[t][2] * inv;
        p[3] = acc[t][3] * inv;
        __builtin_nontemporal_store(p, reinterpret_cast<f32x4*>(abase + t * 16));
        uint2 d;
        d.x = f2bf(p[0]) | ((unsigned)f2bf(p[1]) << 16);
        d.y = f2bf(p[2]) | ((unsigned)f2bf(p[3]) << 16);
        *reinterpret_cast<uint2*>(pbase + t * 16) = d;
    }
    __syncthreads();

    // ---- P @ V (swapped): out^T tile = mfma(v_frag, P_frag). Lane holds
    // out[qrow=l16][dv = w*16 + quad*4 + r] -> one dwordx4 store.
    f32x4 o = {0.f, 0.f, 0.f, 0.f};
    const unsigned short* prow = &u.Pbuf[l16 * PST + quad * 8];
#pragma unroll
    for (int kc = 0; kc < 32; ++kc) {
        short8 a = as_short8(*(const uint4*)(prow + kc * 32));
        uint4 bfrag = (kc == 0) ? pf0 : (kc == 1) ? pf1 : (kc == 2) ? pf2 : (kc == 3) ? pf3
                                      : vb[kc * 64];
        o = __builtin_amdgcn_mfma_f32_16x16x32_bf16(as_short8(bfrag), a, o, 0, 0, 0);
    }
    __builtin_nontemporal_store(
        o, reinterpret_cast<f32x4*>(outp + ((size_t)(rowbase + l16)) * 64 + w * 16 + quad * 4));
}

extern "C" void kernel_launch(void* const* d_in, const int* in_sizes, int n_in,
                              void* d_out, int out_size, void* d_ws, size_t ws_size,
                              hipStream_t stream) {
    (void)in_sizes; (void)n_in; (void)out_size; (void)ws_size;
    const float* q   = (const float*)d_in[0];   // [4,1024,8,64]
    const float* WA  = (const float*)d_in[1];   // [8,64,32]
    const float* WB  = (const float*)d_in[2];   // [8,32,16]
    const float* WAt = (const float*)d_in[3];   // [8,32,64]
    const float* WBt = (const float*)d_in[4];   // [8,16,32]
    const float* qt  = (const float*)d_in[5];   // [4,8,64,1024]
    const float* v   = (const float*)d_in[6];   // [4,8,1024,64]

    float* outp  = (float*)d_out;                           // [4,8,1024,64]
    float* attnp = outp + (size_t)4 * 8 * 1024 * 64;        // [4,8,1024,1024]

    char* ws = (char*)d_ws;
    uint4* qtp = (uint4*)ws;                                // 4 MB
    uint4* vp  = (uint4*)(ws + 4194304);                    // 4 MB

    hipLaunchKernelGGL(repack_kernel, dim3(2048), dim3(256), 0, stream, qt, v, qtp, vp);
    hipLaunchKernelGGL(attn_kernel, dim3(2048), dim3(256), 0, stream,
                       q, WA, WB, WBt, WAt, qtp, vp, outp, attnp);
}